// Round 1
// baseline (1575.953 us; speedup 1.0000x reference)
//
#include <hip/hip_runtime.h>

using u16 = unsigned short;
using bf16x8 = __attribute__((ext_vector_type(8))) short;
using f32x4  = __attribute__((ext_vector_type(4))) float;

#define DIM   1024
#define HW    3840
#define NSEL  4224
#define NK    8224
#define NKPAD 8320
#define NH    16

__device__ __forceinline__ u16 f2bf(float x) {
    unsigned u = __float_as_uint(x);
    return (u16)((u + 0x7FFFu + ((u >> 16) & 1u)) >> 16);
}

// ---------- prep: transpose weights to bf16 WT[n][k] = W[k][n] ----------
__global__ void transpose_w_kernel(const float* __restrict__ Wq, const float* __restrict__ Wk,
                                   const float* __restrict__ Wv, const float* __restrict__ Wo,
                                   u16* __restrict__ WT) {
    const float* src = blockIdx.z == 0 ? Wq : blockIdx.z == 1 ? Wk : blockIdx.z == 2 ? Wv : Wo;
    u16* dst = WT + (size_t)blockIdx.z * DIM * DIM;
    __shared__ float t[32][33];
    int n0 = blockIdx.x * 32, k0 = blockIdx.y * 32;
    int tx = threadIdx.x, ty = threadIdx.y;
#pragma unroll
    for (int j = 0; j < 4; ++j)
        t[ty + 8 * j][tx] = src[(size_t)(k0 + ty + 8 * j) * DIM + n0 + tx];
    __syncthreads();
#pragma unroll
    for (int j = 0; j < 4; ++j)
        dst[(size_t)(n0 + ty + 8 * j) * DIM + k0 + tx] = f2bf(t[tx][ty + 8 * j]);
}

// ---------- prep: q_in[pix][d] = feats_cur[d][pix] + ps[d][pix]  (bf16) ----------
__global__ void build_qin_kernel(const float* __restrict__ fc, const float* __restrict__ ps,
                                 u16* __restrict__ qin) {
    __shared__ float t[32][33];
    int p0 = blockIdx.x * 32, d0 = blockIdx.y * 32;
    int tx = threadIdx.x, ty = threadIdx.y;
#pragma unroll
    for (int j = 0; j < 4; ++j) {
        int d = d0 + ty + 8 * j;
        t[ty + 8 * j][tx] = fc[(size_t)d * HW + p0 + tx] + ps[(size_t)d * HW + p0 + tx];
    }
    __syncthreads();
#pragma unroll
    for (int j = 0; j < 4; ++j)
        qin[(size_t)(p0 + ty + 8 * j) * DIM + d0 + tx] = f2bf(t[tx][ty + 8 * j]);
}

// ---------- prep: k_in rows = [sel(4224) | ext_mem[mem_idx](2000) | glob(2000) | zero-pad] ----------
__global__ void build_kin_kernel(const float* __restrict__ fr, const float* __restrict__ ps,
                                 const float* __restrict__ em, const float* __restrict__ gc,
                                 const int* __restrict__ sel, const int* __restrict__ midx,
                                 const int* __restrict__ gidx, u16* __restrict__ kin) {
    const int row = blockIdx.x;
    u16* dst = kin + (size_t)row * DIM;
    const int t = threadIdx.x;
    if (row < NSEL) {
        const int f = row / 384;
        const int idx = sel[row];
        const float* base = fr + (size_t)f * DIM * HW + idx;
#pragma unroll
        for (int j = 0; j < 4; ++j) {
            int d = t + 256 * j;
            dst[d] = f2bf(base[(size_t)d * HW] + ps[(size_t)d * HW + idx]);
        }
    } else if (row < NSEL + 2000) {
        const float* src = em + (size_t)midx[row - NSEL] * DIM;
#pragma unroll
        for (int j = 0; j < 4; ++j) { int d = t + 256 * j; dst[d] = f2bf(src[d]); }
    } else if (row < NK) {
        const float* src = gc + (size_t)gidx[row - (NSEL + 2000)] * DIM;
#pragma unroll
        for (int j = 0; j < 4; ++j) { int d = t + 256 * j; dst[d] = f2bf(src[d]); }
    } else {
#pragma unroll
        for (int j = 0; j < 4; ++j) dst[t + 256 * j] = 0;
    }
}

// ---------- GEMM: C[m][n] = sum_k A[m][k] * B[n][k], K=1024, 128x128 tile ----------
// mode 0: store bf16 to C (ldc). mode 1: store f32 + r1[o] + r2[o].
__global__ __launch_bounds__(256, 2) void gemm_bt_kernel(const u16* __restrict__ A,
                                                         const u16* __restrict__ B,
                                                         void* __restrict__ Cout,
                                                         const float* __restrict__ r1,
                                                         const float* __restrict__ r2,
                                                         int ldc, int mode) {
    __shared__ __align__(16) u16 As[128 * 64];
    __shared__ __align__(16) u16 Bs[128 * 64];
    const int tid = threadIdx.x;
    const int l = tid & 63;
    const int wv = tid >> 6;
    const int wr = (wv >> 1) * 64, wc = (wv & 1) * 64;
    const int g = l >> 4, lo = l & 15;
    const size_t bm = (size_t)blockIdx.y * 128, bn = (size_t)blockIdx.x * 128;
    const f32x4 fzero = {0.f, 0.f, 0.f, 0.f};

    f32x4 acc[4][4];
#pragma unroll
    for (int i = 0; i < 4; ++i)
#pragma unroll
        for (int j = 0; j < 4; ++j) acc[i][j] = fzero;

    for (int kt = 0; kt < 16; ++kt) {
        const int k0 = kt * 64;
#pragma unroll
        for (int q = 0; q < 4; ++q) {
            int idx = q * 256 + tid;
            int row = idx >> 3, c8 = idx & 7;
            uint4 va  = *(const uint4*)(A + (bm + row) * DIM + k0 + c8 * 8);
            uint4 vbb = *(const uint4*)(B + (bn + row) * DIM + k0 + c8 * 8);
            int sw = c8 ^ (row & 7);                 // XOR swizzle (write side)
            *(uint4*)(As + row * 64 + sw * 8) = va;
            *(uint4*)(Bs + row * 64 + sw * 8) = vbb;
        }
        __syncthreads();
#pragma unroll
        for (int ks = 0; ks < 2; ++ks) {
            bf16x8 af[4], bfv[4];
#pragma unroll
            for (int mi = 0; mi < 4; ++mi) {
                int row = wr + mi * 16 + lo;
                int sw = (ks * 4 + g) ^ (row & 7);   // XOR swizzle (read side)
                af[mi] = *(const bf16x8*)(As + row * 64 + sw * 8);
            }
#pragma unroll
            for (int ni = 0; ni < 4; ++ni) {
                int row = wc + ni * 16 + lo;
                int sw = (ks * 4 + g) ^ (row & 7);
                bfv[ni] = *(const bf16x8*)(Bs + row * 64 + sw * 8);
            }
#pragma unroll
            for (int mi = 0; mi < 4; ++mi)
#pragma unroll
                for (int ni = 0; ni < 4; ++ni)
                    acc[mi][ni] = __builtin_amdgcn_mfma_f32_16x16x32_bf16(af[mi], bfv[ni], acc[mi][ni], 0, 0, 0);
        }
        __syncthreads();
    }

    if (mode == 0) {
        u16* C = (u16*)Cout;
#pragma unroll
        for (int mi = 0; mi < 4; ++mi)
#pragma unroll
            for (int ni = 0; ni < 4; ++ni)
#pragma unroll
                for (int r = 0; r < 4; ++r) {
                    size_t m = bm + wr + mi * 16 + g * 4 + r;
                    size_t n = bn + wc + ni * 16 + lo;
                    C[m * (size_t)ldc + n] = f2bf(acc[mi][ni][r]);
                }
    } else {
        float* C = (float*)Cout;
#pragma unroll
        for (int mi = 0; mi < 4; ++mi)
#pragma unroll
            for (int ni = 0; ni < 4; ++ni)
#pragma unroll
                for (int r = 0; r < 4; ++r) {
                    size_t m = bm + wr + mi * 16 + g * 4 + r;
                    size_t n = bn + wc + ni * 16 + lo;
                    size_t o = m * (size_t)ldc + n;
                    C[o] = acc[mi][ni][r] + r1[o] + r2[o];
                }
    }
}

// ---------- flash attention: 1 wave = 64 queries x 1 head, Kblk=32 (257 blocks) ----------
__global__ __launch_bounds__(256, 1) void attn_kernel(const u16* __restrict__ Q,
                                                      const u16* __restrict__ K,
                                                      const u16* __restrict__ Vt,
                                                      u16* __restrict__ ctx) {
    __shared__ __align__(16) u16 P[4][64][40];   // per wave: [64 q][32 k + 8 pad]
    const int h = blockIdx.y;
    const int tid = threadIdx.x;
    const int l = tid & 63, wv = tid >> 6;
    const int g = l >> 4, lo = l & 15;
    const int q0 = blockIdx.x * 256 + wv * 64;
    const int hoff = h * 64;
    const f32x4 fzero = {0.f, 0.f, 0.f, 0.f};

    bf16x8 qa[4][2];
#pragma unroll
    for (int mi = 0; mi < 4; ++mi)
#pragma unroll
        for (int ks = 0; ks < 2; ++ks)
            qa[mi][ks] = *(const bf16x8*)(Q + (size_t)(q0 + mi * 16 + lo) * DIM + hoff + ks * 32 + g * 8);

    f32x4 acc[4][4];
    float mrow[4][4], lrow[4][4];
#pragma unroll
    for (int mi = 0; mi < 4; ++mi)
#pragma unroll
        for (int ni = 0; ni < 4; ++ni) acc[mi][ni] = fzero;
#pragma unroll
    for (int mi = 0; mi < 4; ++mi)
#pragma unroll
        for (int r = 0; r < 4; ++r) { mrow[mi][r] = -1e30f; lrow[mi][r] = 0.f; }

    for (int kb = 0; kb < 257; ++kb) {
        const int kk = kb * 32;
        bf16x8 kf[2][2];
#pragma unroll
        for (int kt = 0; kt < 2; ++kt)
#pragma unroll
            for (int ks = 0; ks < 2; ++ks)
                kf[kt][ks] = *(const bf16x8*)(K + (size_t)(kk + kt * 16 + lo) * DIM + hoff + ks * 32 + g * 8);

        f32x4 S[4][2];
#pragma unroll
        for (int mi = 0; mi < 4; ++mi)
#pragma unroll
            for (int kt = 0; kt < 2; ++kt) {
                f32x4 s = fzero;
                s = __builtin_amdgcn_mfma_f32_16x16x32_bf16(qa[mi][0], kf[kt][0], s, 0, 0, 0);
                s = __builtin_amdgcn_mfma_f32_16x16x32_bf16(qa[mi][1], kf[kt][1], s, 0, 0, 0);
                S[mi][kt] = s;
            }

#pragma unroll
        for (int mi = 0; mi < 4; ++mi)
#pragma unroll
            for (int r = 0; r < 4; ++r) {
                float s0 = S[mi][0][r] * 0.125f;
                float s1 = S[mi][1][r] * 0.125f;
                float v = fmaxf(s0, s1);
                v = fmaxf(v, __shfl_xor(v, 1));
                v = fmaxf(v, __shfl_xor(v, 2));
                v = fmaxf(v, __shfl_xor(v, 4));
                v = fmaxf(v, __shfl_xor(v, 8));
                float mo = mrow[mi][r];
                float mn = fmaxf(mo, v);
                mrow[mi][r] = mn;
                float fct = __expf(mo - mn);
                float p0 = __expf(s0 - mn);
                float p1 = __expf(s1 - mn);
                float rs = p0 + p1;
                rs += __shfl_xor(rs, 1);
                rs += __shfl_xor(rs, 2);
                rs += __shfl_xor(rs, 4);
                rs += __shfl_xor(rs, 8);
                lrow[mi][r] = lrow[mi][r] * fct + rs;
#pragma unroll
                for (int ni = 0; ni < 4; ++ni) acc[mi][ni][r] *= fct;
                const int pr = mi * 16 + g * 4 + r;
                P[wv][pr][lo]      = f2bf(p0);
                P[wv][pr][16 + lo] = f2bf(p1);
            }
        __syncthreads();

        bf16x8 pa[4], vb[4];
#pragma unroll
        for (int mi = 0; mi < 4; ++mi)
            pa[mi] = *(const bf16x8*)(&P[wv][mi * 16 + lo][g * 8]);
#pragma unroll
        for (int ni = 0; ni < 4; ++ni)
            vb[ni] = *(const bf16x8*)(Vt + (size_t)(hoff + ni * 16 + lo) * NKPAD + kk + g * 8);
#pragma unroll
        for (int mi = 0; mi < 4; ++mi)
#pragma unroll
            for (int ni = 0; ni < 4; ++ni)
                acc[mi][ni] = __builtin_amdgcn_mfma_f32_16x16x32_bf16(pa[mi], vb[ni], acc[mi][ni], 0, 0, 0);
        __syncthreads();
    }

#pragma unroll
    for (int mi = 0; mi < 4; ++mi)
#pragma unroll
        for (int ni = 0; ni < 4; ++ni)
#pragma unroll
            for (int r = 0; r < 4; ++r) {
                float val = acc[mi][ni][r] / lrow[mi][r];
                ctx[(size_t)(q0 + mi * 16 + g * 4 + r) * DIM + hoff + ni * 16 + lo] = f2bf(val);
            }
}

extern "C" void kernel_launch(void* const* d_in, const int* in_sizes, int n_in,
                              void* d_out, int out_size, void* d_ws, size_t ws_size,
                              hipStream_t stream) {
    const float* fc  = (const float*)d_in[0];
    const float* ps  = (const float*)d_in[1];
    const float* fr  = (const float*)d_in[2];
    const float* em  = (const float*)d_in[3];
    const float* gc  = (const float*)d_in[4];
    const float* Wq  = (const float*)d_in[5];
    const float* Wk  = (const float*)d_in[6];
    const float* Wv  = (const float*)d_in[7];
    const float* Wo  = (const float*)d_in[8];
    const int* sel   = (const int*)d_in[9];
    const int* midx  = (const int*)d_in[10];
    const int* gidx  = (const int*)d_in[11];

    char* w = (char*)d_ws;
    u16* WT  = (u16*)(w);                       //  8 MB: 4x [1024][1024] bf16
    u16* qin = (u16*)(w + 8388608ull);          //  7.5 MB [3840][1024]
    u16* kin = (u16*)(w + 16252928ull);         // 16.25 MB [8320][1024]
    u16* Qp  = (u16*)(w + 33292288ull);         //  7.5 MB [3840][1024]
    u16* Kp  = (u16*)(w + 41156608ull);         // 16.25 MB [8320][1024]
    u16* Vt  = (u16*)(w + 58195968ull);         // 16.25 MB [1024][8320]
    u16* ctx = (u16*)(w + 75235328ull);         //  7.5 MB [3840][1024]
    float* out = (float*)d_out;

    transpose_w_kernel<<<dim3(32, 32, 4), dim3(32, 8), 0, stream>>>(Wq, Wk, Wv, Wo, WT);
    build_qin_kernel<<<dim3(120, 32), dim3(32, 8), 0, stream>>>(fc, ps, qin);
    build_kin_kernel<<<dim3(NKPAD), dim3(256), 0, stream>>>(fr, ps, em, gc, sel, midx, gidx, kin);

    // Q = q_in @ Wq  -> bf16 [3840][1024]
    gemm_bt_kernel<<<dim3(8, 30), dim3(256), 0, stream>>>(qin, WT, Qp, nullptr, nullptr, 1024, 0);
    // K = k_in @ Wk  -> bf16 [8320][1024]
    gemm_bt_kernel<<<dim3(8, 65), dim3(256), 0, stream>>>(kin, WT + 1048576, Kp, nullptr, nullptr, 1024, 0);
    // V^T = (k_in @ Wv)^T -> bf16 [1024][8320]
    gemm_bt_kernel<<<dim3(65, 8), dim3(256), 0, stream>>>(WT + 2097152, kin, Vt, nullptr, nullptr, NKPAD, 0);

    attn_kernel<<<dim3(15, NH), dim3(256), 0, stream>>>(Qp, Kp, Vt, ctx);

    // out^T[d][pix] = (ctx @ Wo)[pix][d] + feats_cur[d][pix] + ps[d][pix]  (f32)
    gemm_bt_kernel<<<dim3(30, 8), dim3(256), 0, stream>>>(WT + 3145728, ctx, out, fc, ps, HW, 1);
}

// Round 2
// 749.577 us; speedup vs baseline: 2.1025x; 2.1025x over previous
//
#include <hip/hip_runtime.h>

using u16 = unsigned short;
using bf16x8 = __attribute__((ext_vector_type(8))) short;
using f32x4  = __attribute__((ext_vector_type(4))) float;

#define DIM   1024
#define HW    3840
#define NSEL  4224
#define NK    8224
#define NKPAD 8320
#define NH    16

__device__ __forceinline__ u16 f2bf(float x) {
    unsigned u = __float_as_uint(x);
    return (u16)((u + 0x7FFFu + ((u >> 16) & 1u)) >> 16);
}

// ---------- prep: transpose weights to bf16 WT[n][k] = W[k][n] ----------
__global__ void transpose_w_kernel(const float* __restrict__ Wq, const float* __restrict__ Wk,
                                   const float* __restrict__ Wv, const float* __restrict__ Wo,
                                   u16* __restrict__ WT) {
    const float* src = blockIdx.z == 0 ? Wq : blockIdx.z == 1 ? Wk : blockIdx.z == 2 ? Wv : Wo;
    u16* dst = WT + (size_t)blockIdx.z * DIM * DIM;
    __shared__ float t[32][33];
    int n0 = blockIdx.x * 32, k0 = blockIdx.y * 32;
    int tx = threadIdx.x, ty = threadIdx.y;
#pragma unroll
    for (int j = 0; j < 4; ++j)
        t[ty + 8 * j][tx] = src[(size_t)(k0 + ty + 8 * j) * DIM + n0 + tx];
    __syncthreads();
#pragma unroll
    for (int j = 0; j < 4; ++j)
        dst[(size_t)(n0 + ty + 8 * j) * DIM + k0 + tx] = f2bf(t[tx][ty + 8 * j]);
}

// ---------- prep: q_in[pix][d] = feats_cur[d][pix] + ps[d][pix]  (bf16) ----------
__global__ void build_qin_kernel(const float* __restrict__ fc, const float* __restrict__ ps,
                                 u16* __restrict__ qin) {
    __shared__ float t[32][33];
    int p0 = blockIdx.x * 32, d0 = blockIdx.y * 32;
    int tx = threadIdx.x, ty = threadIdx.y;
#pragma unroll
    for (int j = 0; j < 4; ++j) {
        int d = d0 + ty + 8 * j;
        t[ty + 8 * j][tx] = fc[(size_t)d * HW + p0 + tx] + ps[(size_t)d * HW + p0 + tx];
    }
    __syncthreads();
#pragma unroll
    for (int j = 0; j < 4; ++j)
        qin[(size_t)(p0 + ty + 8 * j) * DIM + d0 + tx] = f2bf(t[tx][ty + 8 * j]);
}

// ---------- prep: k_in rows = [sel(4224) | ext_mem[mem_idx](2000) | glob(2000) | zero-pad] ----------
__global__ void build_kin_kernel(const float* __restrict__ fr, const float* __restrict__ ps,
                                 const float* __restrict__ em, const float* __restrict__ gc,
                                 const int* __restrict__ sel, const int* __restrict__ midx,
                                 const int* __restrict__ gidx, u16* __restrict__ kin) {
    const int row = blockIdx.x;
    u16* dst = kin + (size_t)row * DIM;
    const int t = threadIdx.x;
    if (row < NSEL) {
        const int f = row / 384;
        const int idx = sel[row];
        const float* base = fr + (size_t)f * DIM * HW + idx;
#pragma unroll
        for (int j = 0; j < 4; ++j) {
            int d = t + 256 * j;
            dst[d] = f2bf(base[(size_t)d * HW] + ps[(size_t)d * HW + idx]);
        }
    } else if (row < NSEL + 2000) {
        const float* src = em + (size_t)midx[row - NSEL] * DIM;
#pragma unroll
        for (int j = 0; j < 4; ++j) { int d = t + 256 * j; dst[d] = f2bf(src[d]); }
    } else if (row < NK) {
        const float* src = gc + (size_t)gidx[row - (NSEL + 2000)] * DIM;
#pragma unroll
        for (int j = 0; j < 4; ++j) { int d = t + 256 * j; dst[d] = f2bf(src[d]); }
    } else {
#pragma unroll
        for (int j = 0; j < 4; ++j) dst[t + 256 * j] = 0;
    }
}

// ---------- GEMM: C[m][n] = sum_k A[m][k] * B[n][k], K=1024, 128x128 tile ----------
// mode 0: store f2bf(acc*scale) to C (ldc). mode 1: store f32 + r1[o] + r2[o].
__global__ __launch_bounds__(256, 2) void gemm_bt_kernel(const u16* __restrict__ A,
                                                         const u16* __restrict__ B,
                                                         void* __restrict__ Cout,
                                                         const float* __restrict__ r1,
                                                         const float* __restrict__ r2,
                                                         int ldc, int mode, float scale) {
    __shared__ __align__(16) u16 As[128 * 64];
    __shared__ __align__(16) u16 Bs[128 * 64];
    const int tid = threadIdx.x;
    const int l = tid & 63;
    const int wv = tid >> 6;
    const int wr = (wv >> 1) * 64, wc = (wv & 1) * 64;
    const int g = l >> 4, lo = l & 15;
    const size_t bm = (size_t)blockIdx.y * 128, bn = (size_t)blockIdx.x * 128;
    const f32x4 fzero = {0.f, 0.f, 0.f, 0.f};

    f32x4 acc[4][4];
#pragma unroll
    for (int i = 0; i < 4; ++i)
#pragma unroll
        for (int j = 0; j < 4; ++j) acc[i][j] = fzero;

    for (int kt = 0; kt < 16; ++kt) {
        const int k0 = kt * 64;
#pragma unroll
        for (int q = 0; q < 4; ++q) {
            int idx = q * 256 + tid;
            int row = idx >> 3, c8 = idx & 7;
            uint4 va  = *(const uint4*)(A + (bm + row) * DIM + k0 + c8 * 8);
            uint4 vbb = *(const uint4*)(B + (bn + row) * DIM + k0 + c8 * 8);
            int sw = c8 ^ (row & 7);                 // XOR swizzle (write side)
            *(uint4*)(As + row * 64 + sw * 8) = va;
            *(uint4*)(Bs + row * 64 + sw * 8) = vbb;
        }
        __syncthreads();
#pragma unroll
        for (int ks = 0; ks < 2; ++ks) {
            bf16x8 af[4], bfv[4];
#pragma unroll
            for (int mi = 0; mi < 4; ++mi) {
                int row = wr + mi * 16 + lo;
                int sw = (ks * 4 + g) ^ (row & 7);   // XOR swizzle (read side)
                af[mi] = *(const bf16x8*)(As + row * 64 + sw * 8);
            }
#pragma unroll
            for (int ni = 0; ni < 4; ++ni) {
                int row = wc + ni * 16 + lo;
                int sw = (ks * 4 + g) ^ (row & 7);
                bfv[ni] = *(const bf16x8*)(Bs + row * 64 + sw * 8);
            }
#pragma unroll
            for (int mi = 0; mi < 4; ++mi)
#pragma unroll
                for (int ni = 0; ni < 4; ++ni)
                    acc[mi][ni] = __builtin_amdgcn_mfma_f32_16x16x32_bf16(af[mi], bfv[ni], acc[mi][ni], 0, 0, 0);
        }
        __syncthreads();
    }

    if (mode == 0) {
        u16* C = (u16*)Cout;
#pragma unroll
        for (int mi = 0; mi < 4; ++mi)
#pragma unroll
            for (int ni = 0; ni < 4; ++ni)
#pragma unroll
                for (int r = 0; r < 4; ++r) {
                    size_t m = bm + wr + mi * 16 + g * 4 + r;
                    size_t n = bn + wc + ni * 16 + lo;
                    C[m * (size_t)ldc + n] = f2bf(acc[mi][ni][r] * scale);
                }
    } else {
        float* C = (float*)Cout;
#pragma unroll
        for (int mi = 0; mi < 4; ++mi)
#pragma unroll
            for (int ni = 0; ni < 4; ++ni)
#pragma unroll
                for (int r = 0; r < 4; ++r) {
                    size_t m = bm + wr + mi * 16 + g * 4 + r;
                    size_t n = bn + wc + ni * 16 + lo;
                    size_t o = m * (size_t)ldc + n;
                    C[o] = acc[mi][ni][r] + r1[o] + r2[o];
                }
    }
}

// ---------- split-K flash attention ----------
// 1 block = 32 queries x 1 head; 4 waves split Nk=8224 (64/64/64/65 kb-blocks of 32);
// in-LDS merge of (m, l, acc) at the end. No barriers in the K loop (P is wave-private).
__global__ __launch_bounds__(256, 4) void attn_kernel(const u16* __restrict__ Q,
                                                      const u16* __restrict__ K,
                                                      const u16* __restrict__ Vt,
                                                      u16* __restrict__ ctx) {
    __shared__ __align__(16) u16 P[4][32][40];   // per-wave P tiles; reused as f32 merge buf
    __shared__ float ml[4][32][2];
    __shared__ float invl[32];
    const int h = blockIdx.y;
    const int tid = threadIdx.x;
    const int l = tid & 63, wv = tid >> 6;
    const int g = l >> 4, lo = l & 15;
    const int q0 = blockIdx.x * 32;
    const int hoff = h * 64;
    const f32x4 fzero = {0.f, 0.f, 0.f, 0.f};

    // Q fragments (1/sqrt(dh) scale pre-folded into Q projection)
    bf16x8 qa[2][2];
#pragma unroll
    for (int mi = 0; mi < 2; ++mi)
#pragma unroll
        for (int ks = 0; ks < 2; ++ks)
            qa[mi][ks] = *(const bf16x8*)(Q + (size_t)(q0 + mi * 16 + lo) * DIM + hoff + ks * 32 + g * 8);

    f32x4 acc[2][4];
    float mrow[2][4], lsum[2][4];
#pragma unroll
    for (int mi = 0; mi < 2; ++mi)
#pragma unroll
        for (int ni = 0; ni < 4; ++ni) acc[mi][ni] = fzero;
#pragma unroll
    for (int mi = 0; mi < 2; ++mi)
#pragma unroll
        for (int r = 0; r < 4; ++r) { mrow[mi][r] = -1e30f; lsum[mi][r] = 0.f; }

    const int kb0 = wv * 64;
    const int nb = 64 + (wv == 3 ? 1 : 0);   // 257 blocks total = 8224 keys exactly

    for (int b = 0; b < nb; ++b) {
        const int kk = (kb0 + b) * 32;
        bf16x8 kf[2][2];
#pragma unroll
        for (int kt = 0; kt < 2; ++kt)
#pragma unroll
            for (int ks = 0; ks < 2; ++ks)
                kf[kt][ks] = *(const bf16x8*)(K + (size_t)(kk + kt * 16 + lo) * DIM + hoff + ks * 32 + g * 8);

        f32x4 S[2][2];
#pragma unroll
        for (int mi = 0; mi < 2; ++mi)
#pragma unroll
            for (int kt = 0; kt < 2; ++kt) {
                f32x4 s = __builtin_amdgcn_mfma_f32_16x16x32_bf16(qa[mi][0], kf[kt][0], fzero, 0, 0, 0);
                s = __builtin_amdgcn_mfma_f32_16x16x32_bf16(qa[mi][1], kf[kt][1], s, 0, 0, 0);
                S[mi][kt] = s;
            }

#pragma unroll
        for (int mi = 0; mi < 2; ++mi)
#pragma unroll
            for (int r = 0; r < 4; ++r) {
                float s0 = S[mi][0][r];
                float s1 = S[mi][1][r];
                float v = fmaxf(s0, s1);
                v = fmaxf(v, __shfl_xor(v, 1));
                v = fmaxf(v, __shfl_xor(v, 2));
                v = fmaxf(v, __shfl_xor(v, 4));
                v = fmaxf(v, __shfl_xor(v, 8));
                float mo = mrow[mi][r];
                if (v > mo) {                        // rescale only when max grows (exact)
                    float fct = __expf(mo - v);
                    mrow[mi][r] = v;
                    lsum[mi][r] *= fct;
#pragma unroll
                    for (int ni = 0; ni < 4; ++ni) acc[mi][ni][r] *= fct;
                    mo = v;
                }
                float p0 = __expf(s0 - mo);
                float p1 = __expf(s1 - mo);
                lsum[mi][r] += p0 + p1;              // per-lane partial; reduced after loop
                const int pr = mi * 16 + g * 4 + r;
                P[wv][pr][lo]      = f2bf(p0);
                P[wv][pr][16 + lo] = f2bf(p1);
            }

        bf16x8 pa0 = *(const bf16x8*)(&P[wv][lo][g * 8]);
        bf16x8 pa1 = *(const bf16x8*)(&P[wv][16 + lo][g * 8]);
#pragma unroll
        for (int ni = 0; ni < 4; ++ni) {
            bf16x8 vb = *(const bf16x8*)(Vt + (size_t)(hoff + ni * 16 + lo) * NKPAD + kk + g * 8);
            acc[0][ni] = __builtin_amdgcn_mfma_f32_16x16x32_bf16(pa0, vb, acc[0][ni], 0, 0, 0);
            acc[1][ni] = __builtin_amdgcn_mfma_f32_16x16x32_bf16(pa1, vb, acc[1][ni], 0, 0, 0);
        }
    }

    // row-reduce the deferred l partials (16 lanes per row group)
#pragma unroll
    for (int mi = 0; mi < 2; ++mi)
#pragma unroll
        for (int r = 0; r < 4; ++r) {
            float t = lsum[mi][r];
            t += __shfl_xor(t, 1);
            t += __shfl_xor(t, 2);
            t += __shfl_xor(t, 4);
            t += __shfl_xor(t, 8);
            lsum[mi][r] = t;
        }

    // publish per-wave (m, l)
    if (lo == 0) {
#pragma unroll
        for (int mi = 0; mi < 2; ++mi)
#pragma unroll
            for (int r = 0; r < 4; ++r) {
                int row = mi * 16 + g * 4 + r;
                ml[wv][row][0] = mrow[mi][r];
                ml[wv][row][1] = lsum[mi][r];
            }
    }
    __syncthreads();

    // global m*, l*, per-wave rescale factors
    float scl[2][4];
#pragma unroll
    for (int mi = 0; mi < 2; ++mi)
#pragma unroll
        for (int r = 0; r < 4; ++r) {
            int row = mi * 16 + g * 4 + r;
            float m0 = ml[0][row][0], m1 = ml[1][row][0], m2 = ml[2][row][0], m3 = ml[3][row][0];
            float ms = fmaxf(fmaxf(m0, m1), fmaxf(m2, m3));
            float lt = ml[0][row][1] * __expf(m0 - ms) + ml[1][row][1] * __expf(m1 - ms) +
                       ml[2][row][1] * __expf(m2 - ms) + ml[3][row][1] * __expf(m3 - ms);
            scl[mi][r] = __expf(mrow[mi][r] - ms);
            if (wv == 0 && lo == 0) invl[row] = 1.0f / lt;
        }
#pragma unroll
    for (int mi = 0; mi < 2; ++mi)
#pragma unroll
        for (int ni = 0; ni < 4; ++ni)
#pragma unroll
            for (int r = 0; r < 4; ++r) acc[mi][ni][r] *= scl[mi][r];

    // merge the 4 waves' partial ctx tiles via LDS (reuse P as f32 [4][32][17])
    float* mg = (float*)&P[0][0][0];
    const int crow = tid >> 3, cc = (tid & 7) * 2;
#pragma unroll
    for (int ni = 0; ni < 4; ++ni) {
        __syncthreads();
#pragma unroll
        for (int mi = 0; mi < 2; ++mi)
#pragma unroll
            for (int r = 0; r < 4; ++r)
                mg[(wv * 32 + mi * 16 + g * 4 + r) * 17 + lo] = acc[mi][ni][r];
        __syncthreads();
        float s0 = (mg[crow * 17 + cc]     + mg[(32 + crow) * 17 + cc] +
                    mg[(64 + crow) * 17 + cc] + mg[(96 + crow) * 17 + cc]) * invl[crow];
        float s1 = (mg[crow * 17 + cc + 1] + mg[(32 + crow) * 17 + cc + 1] +
                    mg[(64 + crow) * 17 + cc + 1] + mg[(96 + crow) * 17 + cc + 1]) * invl[crow];
        unsigned pack = (unsigned)f2bf(s0) | ((unsigned)f2bf(s1) << 16);
        *(unsigned*)(ctx + (size_t)(q0 + crow) * DIM + hoff + ni * 16 + cc) = pack;
    }
}

extern "C" void kernel_launch(void* const* d_in, const int* in_sizes, int n_in,
                              void* d_out, int out_size, void* d_ws, size_t ws_size,
                              hipStream_t stream) {
    const float* fc  = (const float*)d_in[0];
    const float* ps  = (const float*)d_in[1];
    const float* fr  = (const float*)d_in[2];
    const float* em  = (const float*)d_in[3];
    const float* gc  = (const float*)d_in[4];
    const float* Wq  = (const float*)d_in[5];
    const float* Wk  = (const float*)d_in[6];
    const float* Wv  = (const float*)d_in[7];
    const float* Wo  = (const float*)d_in[8];
    const int* sel   = (const int*)d_in[9];
    const int* midx  = (const int*)d_in[10];
    const int* gidx  = (const int*)d_in[11];

    char* w = (char*)d_ws;
    u16* WT  = (u16*)(w);                       //  8 MB: 4x [1024][1024] bf16
    u16* qin = (u16*)(w + 8388608ull);          //  7.5 MB [3840][1024]
    u16* kin = (u16*)(w + 16252928ull);         // 16.25 MB [8320][1024]
    u16* Qp  = (u16*)(w + 33292288ull);         //  7.5 MB [3840][1024]
    u16* Kp  = (u16*)(w + 41156608ull);         // 16.25 MB [8320][1024]
    u16* Vt  = (u16*)(w + 58195968ull);         // 16.25 MB [1024][8320]
    u16* ctx = (u16*)(w + 75235328ull);         //  7.5 MB [3840][1024]
    float* out = (float*)d_out;

    transpose_w_kernel<<<dim3(32, 32, 4), dim3(32, 8), 0, stream>>>(Wq, Wk, Wv, Wo, WT);
    build_qin_kernel<<<dim3(120, 32), dim3(32, 8), 0, stream>>>(fc, ps, qin);
    build_kin_kernel<<<dim3(NKPAD), dim3(256), 0, stream>>>(fr, ps, em, gc, sel, midx, gidx, kin);

    // Q = (q_in @ Wq) * 0.125 -> bf16 [3840][1024]  (attention scale folded here)
    gemm_bt_kernel<<<dim3(8, 30), dim3(256), 0, stream>>>(qin, WT, Qp, nullptr, nullptr, 1024, 0, 0.125f);
    // K = k_in @ Wk  -> bf16 [8320][1024]
    gemm_bt_kernel<<<dim3(8, 65), dim3(256), 0, stream>>>(kin, WT + 1048576, Kp, nullptr, nullptr, 1024, 0, 1.0f);
    // V^T = (k_in @ Wv)^T -> bf16 [1024][8320]
    gemm_bt_kernel<<<dim3(65, 8), dim3(256), 0, stream>>>(WT + 2097152, kin, Vt, nullptr, nullptr, NKPAD, 0, 1.0f);

    attn_kernel<<<dim3(120, NH), dim3(256), 0, stream>>>(Qp, Kp, Vt, ctx);

    // out^T[d][pix] = (ctx @ Wo)[pix][d] + feats_cur[d][pix] + ps[d][pix]  (f32)
    gemm_bt_kernel<<<dim3(30, 8), dim3(256), 0, stream>>>(WT + 3145728, ctx, out, fc, ps, HW, 1, 1.0f);
}

// Round 3
// 739.286 us; speedup vs baseline: 2.1317x; 1.0139x over previous
//
#include <hip/hip_runtime.h>

using u16 = unsigned short;
using bf16x8 = __attribute__((ext_vector_type(8))) short;
using f32x4  = __attribute__((ext_vector_type(4))) float;

#define DIM   1024
#define HW    3840
#define NSEL  4224
#define NK    8224
#define NKPAD 8320
#define NH    16

__device__ __forceinline__ u16 f2bf(float x) {
    unsigned u = __float_as_uint(x);
    return (u16)((u + 0x7FFFu + ((u >> 16) & 1u)) >> 16);
}

__device__ __forceinline__ float exp2fast(float x) {
    return __builtin_amdgcn_exp2f(x);
}

// ---------- prep: transpose weights to bf16 WT[n][k] = W[k][n] ----------
__global__ void transpose_w_kernel(const float* __restrict__ Wq, const float* __restrict__ Wk,
                                   const float* __restrict__ Wv, const float* __restrict__ Wo,
                                   u16* __restrict__ WT) {
    const float* src = blockIdx.z == 0 ? Wq : blockIdx.z == 1 ? Wk : blockIdx.z == 2 ? Wv : Wo;
    u16* dst = WT + (size_t)blockIdx.z * DIM * DIM;
    __shared__ float t[32][33];
    int n0 = blockIdx.x * 32, k0 = blockIdx.y * 32;
    int tx = threadIdx.x, ty = threadIdx.y;
#pragma unroll
    for (int j = 0; j < 4; ++j)
        t[ty + 8 * j][tx] = src[(size_t)(k0 + ty + 8 * j) * DIM + n0 + tx];
    __syncthreads();
#pragma unroll
    for (int j = 0; j < 4; ++j)
        dst[(size_t)(n0 + ty + 8 * j) * DIM + k0 + tx] = f2bf(t[tx][ty + 8 * j]);
}

// ---------- prep: q_in[pix][d] = feats_cur[d][pix] + ps[d][pix]  (bf16) ----------
__global__ void build_qin_kernel(const float* __restrict__ fc, const float* __restrict__ ps,
                                 u16* __restrict__ qin) {
    __shared__ float t[32][33];
    int p0 = blockIdx.x * 32, d0 = blockIdx.y * 32;
    int tx = threadIdx.x, ty = threadIdx.y;
#pragma unroll
    for (int j = 0; j < 4; ++j) {
        int d = d0 + ty + 8 * j;
        t[ty + 8 * j][tx] = fc[(size_t)d * HW + p0 + tx] + ps[(size_t)d * HW + p0 + tx];
    }
    __syncthreads();
#pragma unroll
    for (int j = 0; j < 4; ++j)
        qin[(size_t)(p0 + ty + 8 * j) * DIM + d0 + tx] = f2bf(t[tx][ty + 8 * j]);
}

// ---------- prep: k_in rows = [sel(4224) | ext_mem[mem_idx](2000) | glob(2000) | zero-pad] ----------
__global__ void build_kin_kernel(const float* __restrict__ fr, const float* __restrict__ ps,
                                 const float* __restrict__ em, const float* __restrict__ gc,
                                 const int* __restrict__ sel, const int* __restrict__ midx,
                                 const int* __restrict__ gidx, u16* __restrict__ kin) {
    const int row = blockIdx.x;
    u16* dst = kin + (size_t)row * DIM;
    const int t = threadIdx.x;
    if (row < NSEL) {
        const int f = row / 384;
        const int idx = sel[row];
        const float* base = fr + (size_t)f * DIM * HW + idx;
#pragma unroll
        for (int j = 0; j < 4; ++j) {
            int d = t + 256 * j;
            dst[d] = f2bf(base[(size_t)d * HW] + ps[(size_t)d * HW + idx]);
        }
    } else if (row < NSEL + 2000) {
        const float* src = em + (size_t)midx[row - NSEL] * DIM;
#pragma unroll
        for (int j = 0; j < 4; ++j) { int d = t + 256 * j; dst[d] = f2bf(src[d]); }
    } else if (row < NK) {
        const float* src = gc + (size_t)gidx[row - (NSEL + 2000)] * DIM;
#pragma unroll
        for (int j = 0; j < 4; ++j) { int d = t + 256 * j; dst[d] = f2bf(src[d]); }
    } else {
#pragma unroll
        for (int j = 0; j < 4; ++j) dst[t + 256 * j] = 0;
    }
}

// ---------- GEMM: C[m][n] = sum_k A[m][k] * B[n][k], K=1024, 128x128 tile ----------
// mode 0: store f2bf(acc*scale) to C (ldc). mode 1: store f32 + r1[o] + r2[o].
__global__ __launch_bounds__(256, 2) void gemm_bt_kernel(const u16* __restrict__ A,
                                                         const u16* __restrict__ B,
                                                         void* __restrict__ Cout,
                                                         const float* __restrict__ r1,
                                                         const float* __restrict__ r2,
                                                         int ldc, int mode, float scale) {
    __shared__ __align__(16) u16 As[128 * 64];
    __shared__ __align__(16) u16 Bs[128 * 64];
    const int tid = threadIdx.x;
    const int l = tid & 63;
    const int wv = tid >> 6;
    const int wr = (wv >> 1) * 64, wc = (wv & 1) * 64;
    const int g = l >> 4, lo = l & 15;
    const size_t bm = (size_t)blockIdx.y * 128, bn = (size_t)blockIdx.x * 128;
    const f32x4 fzero = {0.f, 0.f, 0.f, 0.f};

    f32x4 acc[4][4];
#pragma unroll
    for (int i = 0; i < 4; ++i)
#pragma unroll
        for (int j = 0; j < 4; ++j) acc[i][j] = fzero;

    for (int kt = 0; kt < 16; ++kt) {
        const int k0 = kt * 64;
#pragma unroll
        for (int q = 0; q < 4; ++q) {
            int idx = q * 256 + tid;
            int row = idx >> 3, c8 = idx & 7;
            uint4 va  = *(const uint4*)(A + (bm + row) * DIM + k0 + c8 * 8);
            uint4 vbb = *(const uint4*)(B + (bn + row) * DIM + k0 + c8 * 8);
            int sw = c8 ^ (row & 7);                 // XOR swizzle (write side)
            *(uint4*)(As + row * 64 + sw * 8) = va;
            *(uint4*)(Bs + row * 64 + sw * 8) = vbb;
        }
        __syncthreads();
#pragma unroll
        for (int ks = 0; ks < 2; ++ks) {
            bf16x8 af[4], bfv[4];
#pragma unroll
            for (int mi = 0; mi < 4; ++mi) {
                int row = wr + mi * 16 + lo;
                int sw = (ks * 4 + g) ^ (row & 7);   // XOR swizzle (read side)
                af[mi] = *(const bf16x8*)(As + row * 64 + sw * 8);
            }
#pragma unroll
            for (int ni = 0; ni < 4; ++ni) {
                int row = wc + ni * 16 + lo;
                int sw = (ks * 4 + g) ^ (row & 7);
                bfv[ni] = *(const bf16x8*)(Bs + row * 64 + sw * 8);
            }
#pragma unroll
            for (int mi = 0; mi < 4; ++mi)
#pragma unroll
                for (int ni = 0; ni < 4; ++ni)
                    acc[mi][ni] = __builtin_amdgcn_mfma_f32_16x16x32_bf16(af[mi], bfv[ni], acc[mi][ni], 0, 0, 0);
        }
        __syncthreads();
    }

    if (mode == 0) {
        u16* C = (u16*)Cout;
#pragma unroll
        for (int mi = 0; mi < 4; ++mi)
#pragma unroll
            for (int ni = 0; ni < 4; ++ni)
#pragma unroll
                for (int r = 0; r < 4; ++r) {
                    size_t m = bm + wr + mi * 16 + g * 4 + r;
                    size_t n = bn + wc + ni * 16 + lo;
                    C[m * (size_t)ldc + n] = f2bf(acc[mi][ni][r] * scale);
                }
    } else {
        float* C = (float*)Cout;
#pragma unroll
        for (int mi = 0; mi < 4; ++mi)
#pragma unroll
            for (int ni = 0; ni < 4; ++ni)
#pragma unroll
                for (int r = 0; r < 4; ++r) {
                    size_t m = bm + wr + mi * 16 + g * 4 + r;
                    size_t n = bn + wc + ni * 16 + lo;
                    size_t o = m * (size_t)ldc + n;
                    C[o] = acc[mi][ni][r] + r1[o] + r2[o];
                }
    }
}

// ---------- split-K flash attention (log2 domain, defer-max, packed P) ----------
// 1 block = 32 queries x 1 head; 4 waves split Nk=8224 (64/64/64/65 kb-blocks of 32).
// Q pre-scaled by 0.125*log2(e); all softmax in exp2 domain.
// K fragment rows permuted (kk+2*lo+kt) so each lane's two P values are adjacent keys
// -> one v_cvt_pk_bf16_f32 + one ds_write_b32; P rows stay in natural key order.
#define THR 50.0f
__global__ __launch_bounds__(256, 4) void attn_kernel(const u16* __restrict__ Q,
                                                      const u16* __restrict__ K,
                                                      const u16* __restrict__ Vt,
                                                      u16* __restrict__ ctx) {
    __shared__ __align__(16) u16 P[4][32][40];   // per-wave P tiles (stride 20 dwords)
    __shared__ float ml[4][32][2];
    __shared__ float invl[32];
    const int h = blockIdx.y;
    const int tid = threadIdx.x;
    const int l = tid & 63, wv = tid >> 6;
    const int g = l >> 4, lo = l & 15;
    const int q0 = blockIdx.x * 32;
    const int hoff = h * 64;
    const f32x4 fzero = {0.f, 0.f, 0.f, 0.f};

    bf16x8 qa[2][2];
#pragma unroll
    for (int mi = 0; mi < 2; ++mi)
#pragma unroll
        for (int ks = 0; ks < 2; ++ks)
            qa[mi][ks] = *(const bf16x8*)(Q + (size_t)(q0 + mi * 16 + lo) * DIM + hoff + ks * 32 + g * 8);

    f32x4 acc[2][4];
    float mrow[2][4], lsum[2][4], pmax[2][4];
#pragma unroll
    for (int mi = 0; mi < 2; ++mi)
#pragma unroll
        for (int ni = 0; ni < 4; ++ni) acc[mi][ni] = fzero;
#pragma unroll
    for (int mi = 0; mi < 2; ++mi)
#pragma unroll
        for (int r = 0; r < 4; ++r) { mrow[mi][r] = -1e30f; lsum[mi][r] = 0.f; pmax[mi][r] = -1e30f; }

    const int kb0 = wv * 64;
    const int nb = 64 + (wv == 3 ? 1 : 0);   // 257 blocks total = 8224 keys exactly

    for (int b = 0; b < nb; ++b) {
        const int kk = (kb0 + b) * 32;
        // permuted K rows: B-frag slot n holds key kk + 2n + kt
        bf16x8 kf[2][2];
#pragma unroll
        for (int kt = 0; kt < 2; ++kt)
#pragma unroll
            for (int ks = 0; ks < 2; ++ks)
                kf[kt][ks] = *(const bf16x8*)(K + (size_t)(kk + 2 * lo + kt) * DIM + hoff + ks * 32 + g * 8);

        f32x4 S[2][2];
#pragma unroll
        for (int mi = 0; mi < 2; ++mi)
#pragma unroll
            for (int kt = 0; kt < 2; ++kt) {
                f32x4 s = __builtin_amdgcn_mfma_f32_16x16x32_bf16(qa[mi][0], kf[kt][0], fzero, 0, 0, 0);
                s = __builtin_amdgcn_mfma_f32_16x16x32_bf16(qa[mi][1], kf[kt][1], s, 0, 0, 0);
                S[mi][kt] = s;
            }

        // update per-lane cumulative row maxes; wave-wide violation check (rare path)
        float viol = -1e30f;
#pragma unroll
        for (int mi = 0; mi < 2; ++mi)
#pragma unroll
            for (int r = 0; r < 4; ++r) {
                pmax[mi][r] = fmaxf(pmax[mi][r], fmaxf(S[mi][0][r], S[mi][1][r]));
                viol = fmaxf(viol, pmax[mi][r] - mrow[mi][r]);
            }
        if (__any(viol > THR)) {
#pragma unroll
            for (int mi = 0; mi < 2; ++mi)
#pragma unroll
                for (int r = 0; r < 4; ++r) {
                    float v = pmax[mi][r];
                    v = fmaxf(v, __shfl_xor(v, 1));
                    v = fmaxf(v, __shfl_xor(v, 2));
                    v = fmaxf(v, __shfl_xor(v, 4));
                    v = fmaxf(v, __shfl_xor(v, 8));
                    float mo = mrow[mi][r];
                    float mn = fmaxf(mo, v);
                    float fct = exp2fast(mo - mn);
                    mrow[mi][r] = mn;
                    lsum[mi][r] *= fct;
#pragma unroll
                    for (int ni = 0; ni < 4; ++ni) acc[mi][ni][r] *= fct;
                }
        }

#pragma unroll
        for (int mi = 0; mi < 2; ++mi)
#pragma unroll
            for (int r = 0; r < 4; ++r) {
                float m = mrow[mi][r];
                float p0 = exp2fast(S[mi][0][r] - m);   // key kk+2*lo
                float p1 = exp2fast(S[mi][1][r] - m);   // key kk+2*lo+1
                lsum[mi][r] += p0 + p1;
                unsigned pk;
                asm("v_cvt_pk_bf16_f32 %0, %1, %2" : "=v"(pk) : "v"(p0), "v"(p1));
                const int pr = mi * 16 + g * 4 + r;
                *(unsigned*)(&P[wv][pr][lo * 2]) = pk;
            }

        bf16x8 pa0 = *(const bf16x8*)(&P[wv][lo][g * 8]);
        bf16x8 pa1 = *(const bf16x8*)(&P[wv][16 + lo][g * 8]);
#pragma unroll
        for (int ni = 0; ni < 4; ++ni) {
            bf16x8 vb = *(const bf16x8*)(Vt + (size_t)(hoff + ni * 16 + lo) * NKPAD + kk + g * 8);
            acc[0][ni] = __builtin_amdgcn_mfma_f32_16x16x32_bf16(pa0, vb, acc[0][ni], 0, 0, 0);
            acc[1][ni] = __builtin_amdgcn_mfma_f32_16x16x32_bf16(pa1, vb, acc[1][ni], 0, 0, 0);
        }
    }

    // row-reduce the deferred l partials (16 lanes per row group)
#pragma unroll
    for (int mi = 0; mi < 2; ++mi)
#pragma unroll
        for (int r = 0; r < 4; ++r) {
            float t = lsum[mi][r];
            t += __shfl_xor(t, 1);
            t += __shfl_xor(t, 2);
            t += __shfl_xor(t, 4);
            t += __shfl_xor(t, 8);
            lsum[mi][r] = t;
        }

    // publish per-wave (m, l)
    if (lo == 0) {
#pragma unroll
        for (int mi = 0; mi < 2; ++mi)
#pragma unroll
            for (int r = 0; r < 4; ++r) {
                int row = mi * 16 + g * 4 + r;
                ml[wv][row][0] = mrow[mi][r];
                ml[wv][row][1] = lsum[mi][r];
            }
    }
    __syncthreads();

    // global m*, l*, per-wave rescale factors (log2 domain)
    float scl[2][4];
#pragma unroll
    for (int mi = 0; mi < 2; ++mi)
#pragma unroll
        for (int r = 0; r < 4; ++r) {
            int row = mi * 16 + g * 4 + r;
            float m0 = ml[0][row][0], m1 = ml[1][row][0], m2 = ml[2][row][0], m3 = ml[3][row][0];
            float ms = fmaxf(fmaxf(m0, m1), fmaxf(m2, m3));
            float lt = ml[0][row][1] * exp2fast(m0 - ms) + ml[1][row][1] * exp2fast(m1 - ms) +
                       ml[2][row][1] * exp2fast(m2 - ms) + ml[3][row][1] * exp2fast(m3 - ms);
            scl[mi][r] = exp2fast(mrow[mi][r] - ms);
            if (wv == 0 && lo == 0) invl[row] = 1.0f / lt;
        }
#pragma unroll
    for (int mi = 0; mi < 2; ++mi)
#pragma unroll
        for (int ni = 0; ni < 4; ++ni)
#pragma unroll
            for (int r = 0; r < 4; ++r) acc[mi][ni][r] *= scl[mi][r];

    // merge the 4 waves' partial ctx tiles via LDS (reuse P as f32 [4][32][17])
    float* mg = (float*)&P[0][0][0];
    const int crow = tid >> 3, cc = (tid & 7) * 2;
#pragma unroll
    for (int ni = 0; ni < 4; ++ni) {
        __syncthreads();
#pragma unroll
        for (int mi = 0; mi < 2; ++mi)
#pragma unroll
            for (int r = 0; r < 4; ++r)
                mg[(wv * 32 + mi * 16 + g * 4 + r) * 17 + lo] = acc[mi][ni][r];
        __syncthreads();
        float s0 = (mg[crow * 17 + cc]     + mg[(32 + crow) * 17 + cc] +
                    mg[(64 + crow) * 17 + cc] + mg[(96 + crow) * 17 + cc]) * invl[crow];
        float s1 = (mg[crow * 17 + cc + 1] + mg[(32 + crow) * 17 + cc + 1] +
                    mg[(64 + crow) * 17 + cc + 1] + mg[(96 + crow) * 17 + cc + 1]) * invl[crow];
        unsigned pack = (unsigned)f2bf(s0) | ((unsigned)f2bf(s1) << 16);
        *(unsigned*)(ctx + (size_t)(q0 + crow) * DIM + hoff + ni * 16 + cc) = pack;
    }
}

extern "C" void kernel_launch(void* const* d_in, const int* in_sizes, int n_in,
                              void* d_out, int out_size, void* d_ws, size_t ws_size,
                              hipStream_t stream) {
    const float* fc  = (const float*)d_in[0];
    const float* ps  = (const float*)d_in[1];
    const float* fr  = (const float*)d_in[2];
    const float* em  = (const float*)d_in[3];
    const float* gc  = (const float*)d_in[4];
    const float* Wq  = (const float*)d_in[5];
    const float* Wk  = (const float*)d_in[6];
    const float* Wv  = (const float*)d_in[7];
    const float* Wo  = (const float*)d_in[8];
    const int* sel   = (const int*)d_in[9];
    const int* midx  = (const int*)d_in[10];
    const int* gidx  = (const int*)d_in[11];

    char* w = (char*)d_ws;
    u16* WT  = (u16*)(w);                       //  8 MB: 4x [1024][1024] bf16
    u16* qin = (u16*)(w + 8388608ull);          //  7.5 MB [3840][1024]
    u16* kin = (u16*)(w + 16252928ull);         // 16.25 MB [8320][1024]
    u16* Qp  = (u16*)(w + 33292288ull);         //  7.5 MB [3840][1024]
    u16* Kp  = (u16*)(w + 41156608ull);         // 16.25 MB [8320][1024]
    u16* Vt  = (u16*)(w + 58195968ull);         // 16.25 MB [1024][8320]
    u16* ctx = (u16*)(w + 75235328ull);         //  7.5 MB [3840][1024]
    float* out = (float*)d_out;

    transpose_w_kernel<<<dim3(32, 32, 4), dim3(32, 8), 0, stream>>>(Wq, Wk, Wv, Wo, WT);
    build_qin_kernel<<<dim3(120, 32), dim3(32, 8), 0, stream>>>(fc, ps, qin);
    build_kin_kernel<<<dim3(NKPAD), dim3(256), 0, stream>>>(fr, ps, em, gc, sel, midx, gidx, kin);

    // Q = (q_in @ Wq) * 0.125*log2(e) -> bf16 (attention scale + exp2 domain folded here)
    gemm_bt_kernel<<<dim3(8, 30), dim3(256), 0, stream>>>(qin, WT, Qp, nullptr, nullptr, 1024, 0, 0.18033688f);
    // K = k_in @ Wk  -> bf16 [8320][1024]
    gemm_bt_kernel<<<dim3(8, 65), dim3(256), 0, stream>>>(kin, WT + 1048576, Kp, nullptr, nullptr, 1024, 0, 1.0f);
    // V^T = (k_in @ Wv)^T -> bf16 [1024][8320]
    gemm_bt_kernel<<<dim3(65, 8), dim3(256), 0, stream>>>(WT + 2097152, kin, Vt, nullptr, nullptr, NKPAD, 0, 1.0f);

    attn_kernel<<<dim3(120, NH), dim3(256), 0, stream>>>(Qp, Kp, Vt, ctx);

    // out^T[d][pix] = (ctx @ Wo)[pix][d] + feats_cur[d][pix] + ps[d][pix]  (f32)
    gemm_bt_kernel<<<dim3(30, 8), dim3(256), 0, stream>>>(WT + 3145728, ctx, out, fc, ps, HW, 1, 1.0f);
}

// Round 4
// 729.494 us; speedup vs baseline: 2.1603x; 1.0134x over previous
//
#include <hip/hip_runtime.h>

using u16 = unsigned short;
using bf16x8 = __attribute__((ext_vector_type(8))) short;
using f32x4  = __attribute__((ext_vector_type(4))) float;

#define DIM   1024
#define HW    3840
#define NSEL  4224
#define NK    8224
#define NKPAD 8320
#define NH    16

__device__ __forceinline__ u16 f2bf(float x) {
    unsigned u = __float_as_uint(x);
    return (u16)((u + 0x7FFFu + ((u >> 16) & 1u)) >> 16);
}

__device__ __forceinline__ float exp2fast(float x) {
    return __builtin_amdgcn_exp2f(x);
}

// ---------- prep: transpose weights to bf16 WT[n][k] = W[k][n] ----------
__global__ void transpose_w_kernel(const float* __restrict__ Wq, const float* __restrict__ Wk,
                                   const float* __restrict__ Wv, const float* __restrict__ Wo,
                                   u16* __restrict__ WT) {
    const float* src = blockIdx.z == 0 ? Wq : blockIdx.z == 1 ? Wk : blockIdx.z == 2 ? Wv : Wo;
    u16* dst = WT + (size_t)blockIdx.z * DIM * DIM;
    __shared__ float t[32][33];
    int n0 = blockIdx.x * 32, k0 = blockIdx.y * 32;
    int tx = threadIdx.x, ty = threadIdx.y;
#pragma unroll
    for (int j = 0; j < 4; ++j)
        t[ty + 8 * j][tx] = src[(size_t)(k0 + ty + 8 * j) * DIM + n0 + tx];
    __syncthreads();
#pragma unroll
    for (int j = 0; j < 4; ++j)
        dst[(size_t)(n0 + ty + 8 * j) * DIM + k0 + tx] = f2bf(t[tx][ty + 8 * j]);
}

// ---------- prep: q_in[pix][d] = feats_cur[d][pix] + ps[d][pix]  (bf16) ----------
__global__ void build_qin_kernel(const float* __restrict__ fc, const float* __restrict__ ps,
                                 u16* __restrict__ qin) {
    __shared__ float t[32][33];
    int p0 = blockIdx.x * 32, d0 = blockIdx.y * 32;
    int tx = threadIdx.x, ty = threadIdx.y;
#pragma unroll
    for (int j = 0; j < 4; ++j) {
        int d = d0 + ty + 8 * j;
        t[ty + 8 * j][tx] = fc[(size_t)d * HW + p0 + tx] + ps[(size_t)d * HW + p0 + tx];
    }
    __syncthreads();
#pragma unroll
    for (int j = 0; j < 4; ++j)
        qin[(size_t)(p0 + ty + 8 * j) * DIM + d0 + tx] = f2bf(t[tx][ty + 8 * j]);
}

// ---------- prep: k_in rows = [sel(4224) | ext_mem[mem_idx](2000) | glob(2000) | zero-pad] ----------
__global__ void build_kin_kernel(const float* __restrict__ fr, const float* __restrict__ ps,
                                 const float* __restrict__ em, const float* __restrict__ gc,
                                 const int* __restrict__ sel, const int* __restrict__ midx,
                                 const int* __restrict__ gidx, u16* __restrict__ kin) {
    const int row = blockIdx.x;
    u16* dst = kin + (size_t)row * DIM;
    const int t = threadIdx.x;
    if (row < NSEL) {
        const int f = row / 384;
        const int idx = sel[row];
        const float* base = fr + (size_t)f * DIM * HW + idx;
#pragma unroll
        for (int j = 0; j < 4; ++j) {
            int d = t + 256 * j;
            dst[d] = f2bf(base[(size_t)d * HW] + ps[(size_t)d * HW + idx]);
        }
    } else if (row < NSEL + 2000) {
        const float* src = em + (size_t)midx[row - NSEL] * DIM;
#pragma unroll
        for (int j = 0; j < 4; ++j) { int d = t + 256 * j; dst[d] = f2bf(src[d]); }
    } else if (row < NK) {
        const float* src = gc + (size_t)gidx[row - (NSEL + 2000)] * DIM;
#pragma unroll
        for (int j = 0; j < 4; ++j) { int d = t + 256 * j; dst[d] = f2bf(src[d]); }
    } else {
#pragma unroll
        for (int j = 0; j < 4; ++j) dst[t + 256 * j] = 0;
    }
}

// ---------- GEMM: C[m][n] = sum_k A[m][k] * B[n][k], K=1024, 128x128 tile ----------
// mode 0: store f2bf(acc*scale) to C (ldc). mode 1: store f32 + r1[o] + r2[o].
__global__ __launch_bounds__(256, 2) void gemm_bt_kernel(const u16* __restrict__ A,
                                                         const u16* __restrict__ B,
                                                         void* __restrict__ Cout,
                                                         const float* __restrict__ r1,
                                                         const float* __restrict__ r2,
                                                         int ldc, int mode, float scale) {
    __shared__ __align__(16) u16 As[128 * 64];
    __shared__ __align__(16) u16 Bs[128 * 64];
    const int tid = threadIdx.x;
    const int l = tid & 63;
    const int wv = tid >> 6;
    const int wr = (wv >> 1) * 64, wc = (wv & 1) * 64;
    const int g = l >> 4, lo = l & 15;
    const size_t bm = (size_t)blockIdx.y * 128, bn = (size_t)blockIdx.x * 128;
    const f32x4 fzero = {0.f, 0.f, 0.f, 0.f};

    f32x4 acc[4][4];
#pragma unroll
    for (int i = 0; i < 4; ++i)
#pragma unroll
        for (int j = 0; j < 4; ++j) acc[i][j] = fzero;

    for (int kt = 0; kt < 16; ++kt) {
        const int k0 = kt * 64;
#pragma unroll
        for (int q = 0; q < 4; ++q) {
            int idx = q * 256 + tid;
            int row = idx >> 3, c8 = idx & 7;
            uint4 va  = *(const uint4*)(A + (bm + row) * DIM + k0 + c8 * 8);
            uint4 vbb = *(const uint4*)(B + (bn + row) * DIM + k0 + c8 * 8);
            int sw = c8 ^ (row & 7);                 // XOR swizzle (write side)
            *(uint4*)(As + row * 64 + sw * 8) = va;
            *(uint4*)(Bs + row * 64 + sw * 8) = vbb;
        }
        __syncthreads();
#pragma unroll
        for (int ks = 0; ks < 2; ++ks) {
            bf16x8 af[4], bfv[4];
#pragma unroll
            for (int mi = 0; mi < 4; ++mi) {
                int row = wr + mi * 16 + lo;
                int sw = (ks * 4 + g) ^ (row & 7);   // XOR swizzle (read side)
                af[mi] = *(const bf16x8*)(As + row * 64 + sw * 8);
            }
#pragma unroll
            for (int ni = 0; ni < 4; ++ni) {
                int row = wc + ni * 16 + lo;
                int sw = (ks * 4 + g) ^ (row & 7);
                bfv[ni] = *(const bf16x8*)(Bs + row * 64 + sw * 8);
            }
#pragma unroll
            for (int mi = 0; mi < 4; ++mi)
#pragma unroll
                for (int ni = 0; ni < 4; ++ni)
                    acc[mi][ni] = __builtin_amdgcn_mfma_f32_16x16x32_bf16(af[mi], bfv[ni], acc[mi][ni], 0, 0, 0);
        }
        __syncthreads();
    }

    if (mode == 0) {
        u16* C = (u16*)Cout;
#pragma unroll
        for (int mi = 0; mi < 4; ++mi)
#pragma unroll
            for (int ni = 0; ni < 4; ++ni)
#pragma unroll
                for (int r = 0; r < 4; ++r) {
                    size_t m = bm + wr + mi * 16 + g * 4 + r;
                    size_t n = bn + wc + ni * 16 + lo;
                    C[m * (size_t)ldc + n] = f2bf(acc[mi][ni][r] * scale);
                }
    } else {
        float* C = (float*)Cout;
#pragma unroll
        for (int mi = 0; mi < 4; ++mi)
#pragma unroll
            for (int ni = 0; ni < 4; ++ni)
#pragma unroll
                for (int r = 0; r < 4; ++r) {
                    size_t m = bm + wr + mi * 16 + g * 4 + r;
                    size_t n = bn + wc + ni * 16 + lo;
                    size_t o = m * (size_t)ldc + n;
                    C[o] = acc[mi][ni][r] + r1[o] + r2[o];
                }
    }
}

// ---------- split-K flash attention, swapped-QK, zero-LDS inner loop ----------
// grid (16 heads, 120 q-tiles): bid%8 == h%8 -> each XCD L2 serves only 2 heads' K/V slices.
// S^T = mfma(K_frag, Q_frag): each lane holds 8 scores of ONE q-row (q = mi*16+lo),
// at keys kk + g*8 + (kt*4+r) thanks to permuted K-row loading (sigma below).
// P packs in-register (v_cvt_pk_bf16_f32) directly into the PV A-fragment. No LDS,
// no cross-lane ops in the common path. K double-buffered in registers.
#define THR 50.0f
__global__ __launch_bounds__(256, 3) void attn_kernel(const u16* __restrict__ Q,
                                                      const u16* __restrict__ K,
                                                      const u16* __restrict__ Vt,
                                                      u16* __restrict__ ctx) {
    __shared__ float mg[4][32][17];
    __shared__ float ml[4][32][2];
    __shared__ float invl[32];
    const int h = blockIdx.x;                 // heads on x => XCD-L2 head locality
    const int q0 = blockIdx.y * 32;
    const int tid = threadIdx.x;
    const int l = tid & 63, wv = tid >> 6;
    const int g = l >> 4, lo = l & 15;
    const int hoff = h * 64;
    const f32x4 fzero = {0.f, 0.f, 0.f, 0.f};

    // Q fragments (B operand): lane holds Q[q0+mi*16+lo][hoff + ks*32 + g*8 ..+7]
    bf16x8 qa[2][2];
#pragma unroll
    for (int mi = 0; mi < 2; ++mi)
#pragma unroll
        for (int ks = 0; ks < 2; ++ks)
            qa[mi][ks] = *(const bf16x8*)(Q + (size_t)(q0 + mi * 16 + lo) * DIM + hoff + ks * 32 + g * 8);

    f32x4 acc[2][4];
#pragma unroll
    for (int mi = 0; mi < 2; ++mi)
#pragma unroll
        for (int ni = 0; ni < 4; ++ni) acc[mi][ni] = fzero;
    float mrow[2] = {-1e30f, -1e30f};
    float lsum[2] = {0.f, 0.f};
    float pmax[2] = {-1e30f, -1e30f};

    const int kb0 = wv * 64;
    const int nb = 64 + (wv == 3 ? 1 : 0);   // 257 blocks total = 8224 keys exactly

    // K A-fragment row permutation: A-row a=lo of kt-tile holds key kk + sig + kt*4
    const int sig = (lo >> 2) * 8 + (lo & 3);
    const u16* Kcol = K + hoff + g * 8;

    bf16x8 kbA[2][2], kbB[2][2];             // [kt][ks], double-buffered

#define LOADK(b, dst)                                                                  \
    {                                                                                  \
        const size_t kkp = (size_t)((kb0 + (b)) * 32 + sig);                           \
        _Pragma("unroll") for (int kt = 0; kt < 2; ++kt)                               \
            _Pragma("unroll") for (int ks = 0; ks < 2; ++ks)                           \
                dst[kt][ks] = *(const bf16x8*)(Kcol + (kkp + kt * 4) * DIM + ks * 32); \
    }

#define BODY(b, curb, nxtb)                                                            \
    {                                                                                  \
        const int kk = (kb0 + (b)) * 32;                                               \
        bf16x8 vb[4];                                                                  \
        _Pragma("unroll") for (int ni = 0; ni < 4; ++ni)                               \
            vb[ni] = *(const bf16x8*)(Vt + (size_t)(hoff + ni * 16 + lo) * NKPAD + kk + g * 8); \
        if ((b) + 1 < nb) LOADK((b) + 1, nxtb);                                        \
        f32x4 S[2][2];                                                                 \
        _Pragma("unroll") for (int mi = 0; mi < 2; ++mi)                               \
            _Pragma("unroll") for (int kt = 0; kt < 2; ++kt) {                         \
                f32x4 s = __builtin_amdgcn_mfma_f32_16x16x32_bf16(curb[kt][0], qa[mi][0], fzero, 0, 0, 0); \
                s = __builtin_amdgcn_mfma_f32_16x16x32_bf16(curb[kt][1], qa[mi][1], s, 0, 0, 0); \
                S[mi][kt] = s;                                                         \
            }                                                                          \
        _Pragma("unroll") for (int mi = 0; mi < 2; ++mi) {                             \
            float m1 = fmaxf(fmaxf(S[mi][0][0], S[mi][0][1]), S[mi][0][2]);            \
            float m2 = fmaxf(fmaxf(S[mi][0][3], S[mi][1][0]), S[mi][1][1]);            \
            float m3 = fmaxf(fmaxf(S[mi][1][2], S[mi][1][3]), m1);                     \
            pmax[mi] = fmaxf(fmaxf(m2, m3), pmax[mi]);                                 \
        }                                                                              \
        if (__any(fmaxf(pmax[0] - mrow[0], pmax[1] - mrow[1]) > THR)) {                \
            _Pragma("unroll") for (int mi = 0; mi < 2; ++mi) {                         \
                float v = pmax[mi];                                                    \
                v = fmaxf(v, __shfl_xor(v, 16));                                       \
                v = fmaxf(v, __shfl_xor(v, 32));                                       \
                float mn = fmaxf(mrow[mi], v);                                         \
                float fct = exp2fast(mrow[mi] - mn);                                   \
                mrow[mi] = mn;                                                         \
                lsum[mi] *= fct;                                                       \
                _Pragma("unroll") for (int r = 0; r < 4; ++r) {                        \
                    float fr_ = __shfl(fct, g * 4 + r);                                \
                    _Pragma("unroll") for (int ni = 0; ni < 4; ++ni) acc[mi][ni][r] *= fr_; \
                }                                                                      \
            }                                                                          \
        }                                                                              \
        _Pragma("unroll") for (int mi = 0; mi < 2; ++mi) {                             \
            float p0 = exp2fast(S[mi][0][0] - mrow[mi]);                               \
            float p1 = exp2fast(S[mi][0][1] - mrow[mi]);                               \
            float p2 = exp2fast(S[mi][0][2] - mrow[mi]);                               \
            float p3 = exp2fast(S[mi][0][3] - mrow[mi]);                               \
            float p4 = exp2fast(S[mi][1][0] - mrow[mi]);                               \
            float p5 = exp2fast(S[mi][1][1] - mrow[mi]);                               \
            float p6 = exp2fast(S[mi][1][2] - mrow[mi]);                               \
            float p7 = exp2fast(S[mi][1][3] - mrow[mi]);                               \
            lsum[mi] += ((p0 + p1) + (p2 + p3)) + ((p4 + p5) + (p6 + p7));             \
            union { unsigned u[4]; bf16x8 v; } pu;                                     \
            asm("v_cvt_pk_bf16_f32 %0, %1, %2" : "=v"(pu.u[0]) : "v"(p0), "v"(p1));    \
            asm("v_cvt_pk_bf16_f32 %0, %1, %2" : "=v"(pu.u[1]) : "v"(p2), "v"(p3));    \
            asm("v_cvt_pk_bf16_f32 %0, %1, %2" : "=v"(pu.u[2]) : "v"(p4), "v"(p5));    \
            asm("v_cvt_pk_bf16_f32 %0, %1, %2" : "=v"(pu.u[3]) : "v"(p6), "v"(p7));    \
            _Pragma("unroll") for (int ni = 0; ni < 4; ++ni)                           \
                acc[mi][ni] = __builtin_amdgcn_mfma_f32_16x16x32_bf16(pu.v, vb[ni], acc[mi][ni], 0, 0, 0); \
        }                                                                              \
    }

    LOADK(0, kbA);
    int b = 0;
    while (true) {
        BODY(b, kbA, kbB);
        if (++b >= nb) break;
        BODY(b, kbB, kbA);
        if (++b >= nb) break;
    }
#undef BODY
#undef LOADK

    // reduce deferred l partials across the 4 g-groups (row q = mi*16+lo)
#pragma unroll
    for (int mi = 0; mi < 2; ++mi) {
        float t = lsum[mi];
        t += __shfl_xor(t, 16);
        t += __shfl_xor(t, 32);
        lsum[mi] = t;
    }

    // publish per-wave (m, l): lanes g==0 cover q rows 0..15 per tile
    if (l < 16) {
        ml[wv][lo][0] = mrow[0];
        ml[wv][lo][1] = lsum[0];
        ml[wv][16 + lo][0] = mrow[1];
        ml[wv][16 + lo][1] = lsum[1];
    }
    __syncthreads();

    // global m*, l*, per-wave rescale factors (log2 domain)
    float scl[2][4];
#pragma unroll
    for (int mi = 0; mi < 2; ++mi)
#pragma unroll
        for (int r = 0; r < 4; ++r) {
            int row = mi * 16 + g * 4 + r;
            float m0 = ml[0][row][0], m1 = ml[1][row][0], m2 = ml[2][row][0], m3 = ml[3][row][0];
            float ms = fmaxf(fmaxf(m0, m1), fmaxf(m2, m3));
            float lt = ml[0][row][1] * exp2fast(m0 - ms) + ml[1][row][1] * exp2fast(m1 - ms) +
                       ml[2][row][1] * exp2fast(m2 - ms) + ml[3][row][1] * exp2fast(m3 - ms);
            scl[mi][r] = exp2fast(ml[wv][row][0] - ms);
            if (wv == 0 && lo == 0) invl[row] = 1.0f / lt;
        }
#pragma unroll
    for (int mi = 0; mi < 2; ++mi)
#pragma unroll
        for (int ni = 0; ni < 4; ++ni)
#pragma unroll
            for (int r = 0; r < 4; ++r) acc[mi][ni][r] *= scl[mi][r];

    // merge the 4 waves' partial ctx tiles via LDS
    float* mgf = &mg[0][0][0];
    const int crow = tid >> 3, cc = (tid & 7) * 2;
#pragma unroll
    for (int ni = 0; ni < 4; ++ni) {
        __syncthreads();
#pragma unroll
        for (int mi = 0; mi < 2; ++mi)
#pragma unroll
            for (int r = 0; r < 4; ++r)
                mgf[(wv * 32 + mi * 16 + g * 4 + r) * 17 + lo] = acc[mi][ni][r];
        __syncthreads();
        float s0 = (mgf[crow * 17 + cc]     + mgf[(32 + crow) * 17 + cc] +
                    mgf[(64 + crow) * 17 + cc] + mgf[(96 + crow) * 17 + cc]) * invl[crow];
        float s1 = (mgf[crow * 17 + cc + 1] + mgf[(32 + crow) * 17 + cc + 1] +
                    mgf[(64 + crow) * 17 + cc + 1] + mgf[(96 + crow) * 17 + cc + 1]) * invl[crow];
        unsigned pack = (unsigned)f2bf(s0) | ((unsigned)f2bf(s1) << 16);
        *(unsigned*)(ctx + (size_t)(q0 + crow) * DIM + hoff + ni * 16 + cc) = pack;
    }
}

extern "C" void kernel_launch(void* const* d_in, const int* in_sizes, int n_in,
                              void* d_out, int out_size, void* d_ws, size_t ws_size,
                              hipStream_t stream) {
    const float* fc  = (const float*)d_in[0];
    const float* ps  = (const float*)d_in[1];
    const float* fr  = (const float*)d_in[2];
    const float* em  = (const float*)d_in[3];
    const float* gc  = (const float*)d_in[4];
    const float* Wq  = (const float*)d_in[5];
    const float* Wk  = (const float*)d_in[6];
    const float* Wv  = (const float*)d_in[7];
    const float* Wo  = (const float*)d_in[8];
    const int* sel   = (const int*)d_in[9];
    const int* midx  = (const int*)d_in[10];
    const int* gidx  = (const int*)d_in[11];

    char* w = (char*)d_ws;
    u16* WT  = (u16*)(w);                       //  8 MB: 4x [1024][1024] bf16
    u16* qin = (u16*)(w + 8388608ull);          //  7.5 MB [3840][1024]
    u16* kin = (u16*)(w + 16252928ull);         // 16.25 MB [8320][1024]
    u16* Qp  = (u16*)(w + 33292288ull);         //  7.5 MB [3840][1024]
    u16* Kp  = (u16*)(w + 41156608ull);         // 16.25 MB [8320][1024]
    u16* Vt  = (u16*)(w + 58195968ull);         // 16.25 MB [1024][8320]
    u16* ctx = (u16*)(w + 75235328ull);         //  7.5 MB [3840][1024]
    float* out = (float*)d_out;

    transpose_w_kernel<<<dim3(32, 32, 4), dim3(32, 8), 0, stream>>>(Wq, Wk, Wv, Wo, WT);
    build_qin_kernel<<<dim3(120, 32), dim3(32, 8), 0, stream>>>(fc, ps, qin);
    build_kin_kernel<<<dim3(NKPAD), dim3(256), 0, stream>>>(fr, ps, em, gc, sel, midx, gidx, kin);

    // Q = (q_in @ Wq) * 0.125*log2(e) -> bf16 (attention scale + exp2 domain folded here)
    gemm_bt_kernel<<<dim3(8, 30), dim3(256), 0, stream>>>(qin, WT, Qp, nullptr, nullptr, 1024, 0, 0.18033688f);
    // K = k_in @ Wk  -> bf16 [8320][1024]
    gemm_bt_kernel<<<dim3(8, 65), dim3(256), 0, stream>>>(kin, WT + 1048576, Kp, nullptr, nullptr, 1024, 0, 1.0f);
    // V^T = (k_in @ Wv)^T -> bf16 [1024][8320]
    gemm_bt_kernel<<<dim3(65, 8), dim3(256), 0, stream>>>(WT + 2097152, kin, Vt, nullptr, nullptr, NKPAD, 0, 1.0f);

    attn_kernel<<<dim3(NH, 120), dim3(256), 0, stream>>>(Qp, Kp, Vt, ctx);

    // out^T[d][pix] = (ctx @ Wo)[pix][d] + feats_cur[d][pix] + ps[d][pix]  (f32)
    gemm_bt_kernel<<<dim3(30, 8), dim3(256), 0, stream>>>(WT + 3145728, ctx, out, fc, ps, HW, 1, 1.0f);
}

// Round 5
// 435.987 us; speedup vs baseline: 3.6147x; 1.6732x over previous
//
#include <hip/hip_runtime.h>

using u16 = unsigned short;
using bf16x8 = __attribute__((ext_vector_type(8))) short;
using f32x4  = __attribute__((ext_vector_type(4))) float;

#define DIM   1024
#define HW    3840
#define NSEL  4224
#define NK    8224
#define NKPAD 8320
#define NH    16
#define KVB   64
#define THR   50.0f

typedef __attribute__((address_space(1))) const unsigned GU;
typedef __attribute__((address_space(3))) unsigned LU;

__device__ __forceinline__ u16 f2bf(float x) {
    unsigned u = __float_as_uint(x);
    return (u16)((u + 0x7FFFu + ((u >> 16) & 1u)) >> 16);
}

__device__ __forceinline__ float exp2fast(float x) {
    return __builtin_amdgcn_exp2f(x);
}

// ---------- prep: transpose weights to bf16 WT[n][k] = W[k][n] ----------
__global__ void transpose_w_kernel(const float* __restrict__ Wq, const float* __restrict__ Wk,
                                   const float* __restrict__ Wv, const float* __restrict__ Wo,
                                   u16* __restrict__ WT) {
    const float* src = blockIdx.z == 0 ? Wq : blockIdx.z == 1 ? Wk : blockIdx.z == 2 ? Wv : Wo;
    u16* dst = WT + (size_t)blockIdx.z * DIM * DIM;
    __shared__ float t[32][33];
    int n0 = blockIdx.x * 32, k0 = blockIdx.y * 32;
    int tx = threadIdx.x, ty = threadIdx.y;
#pragma unroll
    for (int j = 0; j < 4; ++j)
        t[ty + 8 * j][tx] = src[(size_t)(k0 + ty + 8 * j) * DIM + n0 + tx];
    __syncthreads();
#pragma unroll
    for (int j = 0; j < 4; ++j)
        dst[(size_t)(n0 + ty + 8 * j) * DIM + k0 + tx] = f2bf(t[tx][ty + 8 * j]);
}

// ---------- prep: q_in[pix][d] = feats_cur[d][pix] + ps[d][pix]  (bf16) ----------
__global__ void build_qin_kernel(const float* __restrict__ fc, const float* __restrict__ ps,
                                 u16* __restrict__ qin) {
    __shared__ float t[32][33];
    int p0 = blockIdx.x * 32, d0 = blockIdx.y * 32;
    int tx = threadIdx.x, ty = threadIdx.y;
#pragma unroll
    for (int j = 0; j < 4; ++j) {
        int d = d0 + ty + 8 * j;
        t[ty + 8 * j][tx] = fc[(size_t)d * HW + p0 + tx] + ps[(size_t)d * HW + p0 + tx];
    }
    __syncthreads();
#pragma unroll
    for (int j = 0; j < 4; ++j)
        qin[(size_t)(p0 + ty + 8 * j) * DIM + d0 + tx] = f2bf(t[tx][ty + 8 * j]);
}

// ---------- prep: k_in rows = [sel(4224) | ext_mem[mem_idx](2000) | glob(2000) | zero-pad] ----------
__global__ void build_kin_kernel(const float* __restrict__ fr, const float* __restrict__ ps,
                                 const float* __restrict__ em, const float* __restrict__ gc,
                                 const int* __restrict__ sel, const int* __restrict__ midx,
                                 const int* __restrict__ gidx, u16* __restrict__ kin) {
    const int row = blockIdx.x;
    u16* dst = kin + (size_t)row * DIM;
    const int t = threadIdx.x;
    if (row < NSEL) {
        const int f = row / 384;
        const int idx = sel[row];
        const float* base = fr + (size_t)f * DIM * HW + idx;
#pragma unroll
        for (int j = 0; j < 4; ++j) {
            int d = t + 256 * j;
            dst[d] = f2bf(base[(size_t)d * HW] + ps[(size_t)d * HW + idx]);
        }
    } else if (row < NSEL + 2000) {
        const float* src = em + (size_t)midx[row - NSEL] * DIM;
#pragma unroll
        for (int j = 0; j < 4; ++j) { int d = t + 256 * j; dst[d] = f2bf(src[d]); }
    } else if (row < NK) {
        const float* src = gc + (size_t)gidx[row - (NSEL + 2000)] * DIM;
#pragma unroll
        for (int j = 0; j < 4; ++j) { int d = t + 256 * j; dst[d] = f2bf(src[d]); }
    } else {
#pragma unroll
        for (int j = 0; j < 4; ++j) dst[t + 256 * j] = 0;
    }
}

// ---------- GEMM: C[m][n] = sum_k A[m][k] * B[n][k], K=1024, 128x128 tile ----------
// mode 0: bf16 store at m*ldc+n (scaled). mode 1: f32 + r1 + r2. mode 2: bf16 head-major
// store at (n>>6)*(NKPAD*64) + m*64 + (n&63).
__global__ __launch_bounds__(256, 2) void gemm_bt_kernel(const u16* __restrict__ A,
                                                         const u16* __restrict__ B,
                                                         void* __restrict__ Cout,
                                                         const float* __restrict__ r1,
                                                         const float* __restrict__ r2,
                                                         int ldc, int mode, float scale) {
    __shared__ __align__(16) u16 As[128 * 64];
    __shared__ __align__(16) u16 Bs[128 * 64];
    const int tid = threadIdx.x;
    const int l = tid & 63;
    const int wv = tid >> 6;
    const int wr = (wv >> 1) * 64, wc = (wv & 1) * 64;
    const int g = l >> 4, lo = l & 15;
    const size_t bm = (size_t)blockIdx.y * 128, bn = (size_t)blockIdx.x * 128;
    const f32x4 fzero = {0.f, 0.f, 0.f, 0.f};

    f32x4 acc[4][4];
#pragma unroll
    for (int i = 0; i < 4; ++i)
#pragma unroll
        for (int j = 0; j < 4; ++j) acc[i][j] = fzero;

    for (int kt = 0; kt < 16; ++kt) {
        const int k0 = kt * 64;
#pragma unroll
        for (int q = 0; q < 4; ++q) {
            int idx = q * 256 + tid;
            int row = idx >> 3, c8 = idx & 7;
            uint4 va  = *(const uint4*)(A + (bm + row) * DIM + k0 + c8 * 8);
            uint4 vbb = *(const uint4*)(B + (bn + row) * DIM + k0 + c8 * 8);
            int sw = c8 ^ (row & 7);
            *(uint4*)(As + row * 64 + sw * 8) = va;
            *(uint4*)(Bs + row * 64 + sw * 8) = vbb;
        }
        __syncthreads();
#pragma unroll
        for (int ks = 0; ks < 2; ++ks) {
            bf16x8 af[4], bfv[4];
#pragma unroll
            for (int mi = 0; mi < 4; ++mi) {
                int row = wr + mi * 16 + lo;
                int sw = (ks * 4 + g) ^ (row & 7);
                af[mi] = *(const bf16x8*)(As + row * 64 + sw * 8);
            }
#pragma unroll
            for (int ni = 0; ni < 4; ++ni) {
                int row = wc + ni * 16 + lo;
                int sw = (ks * 4 + g) ^ (row & 7);
                bfv[ni] = *(const bf16x8*)(Bs + row * 64 + sw * 8);
            }
#pragma unroll
            for (int mi = 0; mi < 4; ++mi)
#pragma unroll
                for (int ni = 0; ni < 4; ++ni)
                    acc[mi][ni] = __builtin_amdgcn_mfma_f32_16x16x32_bf16(af[mi], bfv[ni], acc[mi][ni], 0, 0, 0);
        }
        __syncthreads();
    }

    if (mode == 0) {
        u16* C = (u16*)Cout;
#pragma unroll
        for (int mi = 0; mi < 4; ++mi)
#pragma unroll
            for (int ni = 0; ni < 4; ++ni)
#pragma unroll
                for (int r = 0; r < 4; ++r) {
                    size_t m = bm + wr + mi * 16 + g * 4 + r;
                    size_t n = bn + wc + ni * 16 + lo;
                    C[m * (size_t)ldc + n] = f2bf(acc[mi][ni][r] * scale);
                }
    } else if (mode == 2) {
        u16* C = (u16*)Cout;
#pragma unroll
        for (int mi = 0; mi < 4; ++mi)
#pragma unroll
            for (int ni = 0; ni < 4; ++ni)
#pragma unroll
                for (int r = 0; r < 4; ++r) {
                    size_t m = bm + wr + mi * 16 + g * 4 + r;
                    size_t n = bn + wc + ni * 16 + lo;
                    size_t o = (n >> 6) * ((size_t)NKPAD * 64) + m * 64 + (n & 63);
                    C[o] = f2bf(acc[mi][ni][r] * scale);
                }
    } else {
        float* C = (float*)Cout;
#pragma unroll
        for (int mi = 0; mi < 4; ++mi)
#pragma unroll
            for (int ni = 0; ni < 4; ++ni)
#pragma unroll
                for (int r = 0; r < 4; ++r) {
                    size_t m = bm + wr + mi * 16 + g * 4 + r;
                    size_t n = bn + wc + ni * 16 + lo;
                    size_t o = m * (size_t)ldc + n;
                    C[o] = acc[mi][ni][r] + r1[o] + r2[o];
                }
    }
}

// ---------- flash attention: 4 waves x 32 q-rows, LDS-shared K/V (KVB=64), dbuf ----------
// K' head-major [NH][NKPAD][64]; V^T d-major [1024][NKPAD].
// LDS K block [64 key-rows][128B], chunk swizzle hK(row) = (row&3)|(((row>>3)&1)<<2).
// LDS V block [64 d-rows][128B], chunk swizzle (row&7). Sources pre-swizzled (G21).
// Lane algebra identical to verified R4: score(q=mi*16+lo, key=kk+(kt>>1)*32+g*8+(kt&1)*4+r).
__global__ __launch_bounds__(256, 3) void attn_kernel(const u16* __restrict__ Q,
                                                      const u16* __restrict__ Kh,
                                                      const u16* __restrict__ Vt,
                                                      u16* __restrict__ ctx) {
    __shared__ __align__(16) u16 Kl[2][4096];
    __shared__ __align__(16) u16 Vl[2][4096];
    __shared__ float invl_s[4][32];
    const int h = blockIdx.x;                 // bid%8 = h%8 -> 2 heads per XCD L2
    const int tid = threadIdx.x;
    const int l = tid & 63, wv = tid >> 6;
    const int g = l >> 4, lo = l & 15;
    const int hoff = h * 64;
    const int qw = blockIdx.y * 128 + wv * 32;
    const f32x4 fzero = {0.f, 0.f, 0.f, 0.f};
    const int sig = (lo >> 2) * 8 + (lo & 3);

    const u16* Ksrc = Kh + (size_t)h * NKPAD * 64;
    const u16* Vsrc = Vt + (size_t)hoff * NKPAD;

    bf16x8 qa[2][2];
#pragma unroll
    for (int mi = 0; mi < 2; ++mi)
#pragma unroll
        for (int ks = 0; ks < 2; ++ks)
            qa[mi][ks] = *(const bf16x8*)(Q + (size_t)(qw + mi * 16 + lo) * DIM + hoff + ks * 32 + g * 8);

    f32x4 acc[2][4];
#pragma unroll
    for (int mi = 0; mi < 2; ++mi)
#pragma unroll
        for (int ni = 0; ni < 4; ++ni) acc[mi][ni] = fzero;
    float mrow[2] = {-1e30f, -1e30f};
    float lsum[2] = {0.f, 0.f};
    float pmax[2] = {-1e30f, -1e30f};

#define STAGE(BUF, IT)                                                                          \
    {                                                                                           \
        const int kks = (IT) * KVB;                                                             \
        _Pragma("unroll") for (int j = 0; j < 2; ++j) {                                         \
            const int inst = wv * 2 + j;                                                        \
            const int r_ = inst * 8 + (l >> 3);                                                 \
            const int c_ = l & 7;                                                               \
            const int hk_ = ((l >> 3) & 3) | ((inst & 1) << 2);                                 \
            const u16* gK = Ksrc + (size_t)(kks + r_) * 64 + ((c_ ^ hk_) * 8);                  \
            __builtin_amdgcn_global_load_lds((GU*)gK, (LU*)&Kl[BUF][inst * 512], 16, 0, 0);     \
            const u16* gV = Vsrc + (size_t)r_ * NKPAD + kks + ((c_ ^ (r_ & 7)) * 8);            \
            __builtin_amdgcn_global_load_lds((GU*)gV, (LU*)&Vl[BUF][inst * 512], 16, 0, 0);     \
        }                                                                                       \
    }

#define COMPUTE(BUF, NT, NS)                                                                    \
    {                                                                                           \
        f32x4 S[2][4];                                                                          \
        _Pragma("unroll") for (int kp = 0; kp < (NT) / 2; ++kp) {                               \
            bf16x8 kf[2][2];                                                                    \
            _Pragma("unroll") for (int k2 = 0; k2 < 2; ++k2)                                    \
                _Pragma("unroll") for (int ks = 0; ks < 2; ++ks) {                              \
                    const int kt = kp * 2 + k2;                                                 \
                    const int row = (kt >> 1) * 32 + (kt & 1) * 4 + sig;                        \
                    const int hk_ = (row & 3) | (((row >> 3) & 1) << 2);                        \
                    const int ck = (ks * 4 + g) ^ hk_;                                          \
                    kf[k2][ks] = *(const bf16x8*)(&Kl[BUF][row * 64 + ck * 8]);                 \
                }                                                                               \
            _Pragma("unroll") for (int mi = 0; mi < 2; ++mi)                                    \
                _Pragma("unroll") for (int k2 = 0; k2 < 2; ++k2) {                              \
                    f32x4 s_ = __builtin_amdgcn_mfma_f32_16x16x32_bf16(kf[k2][0], qa[mi][0], fzero, 0, 0, 0); \
                    S[mi][kp * 2 + k2] = __builtin_amdgcn_mfma_f32_16x16x32_bf16(kf[k2][1], qa[mi][1], s_, 0, 0, 0); \
                }                                                                               \
        }                                                                                       \
        _Pragma("unroll") for (int mi = 0; mi < 2; ++mi)                                        \
            _Pragma("unroll") for (int kt = 0; kt < (NT); ++kt) {                               \
                f32x4 sv = S[mi][kt];                                                           \
                pmax[mi] = fmaxf(pmax[mi], fmaxf(fmaxf(sv[0], sv[1]), fmaxf(sv[2], sv[3])));    \
            }                                                                                   \
        if (__any(fmaxf(pmax[0] - mrow[0], pmax[1] - mrow[1]) > THR)) {                         \
            _Pragma("unroll") for (int mi = 0; mi < 2; ++mi) {                                  \
                float v = pmax[mi];                                                             \
                v = fmaxf(v, __shfl_xor(v, 16));                                                \
                v = fmaxf(v, __shfl_xor(v, 32));                                                \
                float mn = fmaxf(mrow[mi], v);                                                  \
                float fct = exp2fast(mrow[mi] - mn);                                            \
                mrow[mi] = mn;                                                                  \
                lsum[mi] *= fct;                                                                \
                _Pragma("unroll") for (int r = 0; r < 4; ++r) {                                 \
                    float fr_ = __shfl(fct, g * 4 + r);                                         \
                    _Pragma("unroll") for (int ni = 0; ni < 4; ++ni) acc[mi][ni][r] *= fr_;     \
                }                                                                               \
            }                                                                                   \
        }                                                                                       \
        _Pragma("unroll") for (int s = 0; s < (NS); ++s) {                                      \
            bf16x8 vb[4];                                                                       \
            _Pragma("unroll") for (int ni = 0; ni < 4; ++ni) {                                  \
                const int row = ni * 16 + lo;                                                   \
                const int ck = (s * 4 + g) ^ (row & 7);                                         \
                vb[ni] = *(const bf16x8*)(&Vl[BUF][row * 64 + ck * 8]);                         \
            }                                                                                   \
            _Pragma("unroll") for (int mi = 0; mi < 2; ++mi) {                                  \
                float p0 = exp2fast(S[mi][2 * s][0] - mrow[mi]);                                \
                float p1 = exp2fast(S[mi][2 * s][1] - mrow[mi]);                                \
                float p2 = exp2fast(S[mi][2 * s][2] - mrow[mi]);                                \
                float p3 = exp2fast(S[mi][2 * s][3] - mrow[mi]);                                \
                float p4 = exp2fast(S[mi][2 * s + 1][0] - mrow[mi]);                            \
                float p5 = exp2fast(S[mi][2 * s + 1][1] - mrow[mi]);                            \
                float p6 = exp2fast(S[mi][2 * s + 1][2] - mrow[mi]);                            \
                float p7 = exp2fast(S[mi][2 * s + 1][3] - mrow[mi]);                            \
                lsum[mi] += ((p0 + p1) + (p2 + p3)) + ((p4 + p5) + (p6 + p7));                  \
                union { unsigned u[4]; bf16x8 v; } pu;                                          \
                asm("v_cvt_pk_bf16_f32 %0, %1, %2" : "=v"(pu.u[0]) : "v"(p0), "v"(p1));         \
                asm("v_cvt_pk_bf16_f32 %0, %1, %2" : "=v"(pu.u[1]) : "v"(p2), "v"(p3));         \
                asm("v_cvt_pk_bf16_f32 %0, %1, %2" : "=v"(pu.u[2]) : "v"(p4), "v"(p5));         \
                asm("v_cvt_pk_bf16_f32 %0, %1, %2" : "=v"(pu.u[3]) : "v"(p6), "v"(p7));         \
                _Pragma("unroll") for (int ni = 0; ni < 4; ++ni)                                \
                    acc[mi][ni] = __builtin_amdgcn_mfma_f32_16x16x32_bf16(pu.v, vb[ni], acc[mi][ni], 0, 0, 0); \
            }                                                                                   \
        }                                                                                       \
    }

    STAGE(0, 0)
    asm volatile("s_waitcnt vmcnt(0)" ::: "memory");
    __syncthreads();

#pragma unroll 1
    for (int it = 0; it < 128; it += 2) {
        STAGE(1, it + 1)
        COMPUTE(0, 4, 2)
        asm volatile("s_waitcnt vmcnt(0)" ::: "memory");
        __syncthreads();
        STAGE(0, it + 2)          // it=126 stages the tail window (keys 8192..8255)
        COMPUTE(1, 4, 2)
        asm volatile("s_waitcnt vmcnt(0)" ::: "memory");
        __syncthreads();
    }
    // tail: keys 8192..8223 (32 real keys; zero-padded rows never touched)
    COMPUTE(0, 2, 1)
#undef COMPUTE
#undef STAGE

    // row totals: sum l partials across the 4 g-lanes of each q-row
#pragma unroll
    for (int mi = 0; mi < 2; ++mi) {
        float t = lsum[mi];
        t += __shfl_xor(t, 16);
        t += __shfl_xor(t, 32);
        lsum[mi] = t;
    }
    // broadcast 1/l through per-wave LDS (acc rows are g*4+r, state rows are lo)
    if (l < 16) {
        invl_s[wv][lo] = 1.0f / lsum[0];
        invl_s[wv][16 + lo] = 1.0f / lsum[1];
    }
#pragma unroll
    for (int mi = 0; mi < 2; ++mi)
#pragma unroll
        for (int ni = 0; ni < 4; ++ni)
#pragma unroll
            for (int r = 0; r < 4; ++r) {
                float val = acc[mi][ni][r] * invl_s[wv][mi * 16 + g * 4 + r];
                ctx[(size_t)(qw + mi * 16 + g * 4 + r) * DIM + hoff + ni * 16 + lo] = f2bf(val);
            }
}

extern "C" void kernel_launch(void* const* d_in, const int* in_sizes, int n_in,
                              void* d_out, int out_size, void* d_ws, size_t ws_size,
                              hipStream_t stream) {
    const float* fc  = (const float*)d_in[0];
    const float* ps  = (const float*)d_in[1];
    const float* fr  = (const float*)d_in[2];
    const float* em  = (const float*)d_in[3];
    const float* gc  = (const float*)d_in[4];
    const float* Wq  = (const float*)d_in[5];
    const float* Wk  = (const float*)d_in[6];
    const float* Wv  = (const float*)d_in[7];
    const float* Wo  = (const float*)d_in[8];
    const int* sel   = (const int*)d_in[9];
    const int* midx  = (const int*)d_in[10];
    const int* gidx  = (const int*)d_in[11];

    char* w = (char*)d_ws;
    u16* WT  = (u16*)(w);                       //  8 MB: 4x [1024][1024] bf16
    u16* qin = (u16*)(w + 8388608ull);          //  7.5 MB [3840][1024]
    u16* kin = (u16*)(w + 16252928ull);         // 16.25 MB [8320][1024]
    u16* Qp  = (u16*)(w + 33292288ull);         //  7.5 MB [3840][1024]
    u16* Kp  = (u16*)(w + 41156608ull);         // 16.25 MB [16][8320][64] head-major
    u16* Vt  = (u16*)(w + 58195968ull);         // 16.25 MB [1024][8320]
    u16* ctx = (u16*)(w + 75235328ull);         //  7.5 MB [3840][1024]
    float* out = (float*)d_out;

    transpose_w_kernel<<<dim3(32, 32, 4), dim3(32, 8), 0, stream>>>(Wq, Wk, Wv, Wo, WT);
    build_qin_kernel<<<dim3(120, 32), dim3(32, 8), 0, stream>>>(fc, ps, qin);
    build_kin_kernel<<<dim3(NKPAD), dim3(256), 0, stream>>>(fr, ps, em, gc, sel, midx, gidx, kin);

    // Q = (q_in @ Wq) * 0.125*log2(e) -> bf16 (attention scale + exp2 domain folded here)
    gemm_bt_kernel<<<dim3(8, 30), dim3(256), 0, stream>>>(qin, WT, Qp, nullptr, nullptr, 1024, 0, 0.18033688f);
    // K' = k_in @ Wk -> bf16 head-major [16][8320][64]
    gemm_bt_kernel<<<dim3(8, 65), dim3(256), 0, stream>>>(kin, WT + 1048576, Kp, nullptr, nullptr, 1024, 2, 1.0f);
    // V^T = (k_in @ Wv)^T -> bf16 [1024][8320]
    gemm_bt_kernel<<<dim3(65, 8), dim3(256), 0, stream>>>(WT + 2097152, kin, Vt, nullptr, nullptr, NKPAD, 0, 1.0f);

    attn_kernel<<<dim3(NH, 30), dim3(256), 0, stream>>>(Qp, Kp, Vt, ctx);

    // out^T[d][pix] = (ctx @ Wo)[pix][d] + feats_cur[d][pix] + ps[d][pix]  (f32)
    gemm_bt_kernel<<<dim3(30, 8), dim3(256), 0, stream>>>(WT + 3145728, ctx, out, fc, ps, HW, 1, 1.0f);
}